// Round 13
// baseline (288.929 us; speedup 1.0000x reference)
//
#include <hip/hip_runtime.h>
#include <math.h>

// Problem constants (fixed by the reference)
#define B_  8
#define C_  256
#define N_  4096        // H*W
#define NJC (N_ / 128)  // 32 j-iterations of 128
#define PLD 136         // p_s row stride in shorts (128 + 8 pad)
#define LOG2E 1.4426950408889634f

using frag  = __attribute__((ext_vector_type(8))) short;   // 8 bf16 = 16 B
using f32x4 = __attribute__((ext_vector_type(4))) float;

__device__ __forceinline__ unsigned short f2bf(float f) {   // RNE fp32 -> bf16
    unsigned u = __float_as_uint(f);
    u += 0x7fffu + ((u >> 16) & 1u);
    return (unsigned short)(u >> 16);
}
__device__ __forceinline__ float bf2f(unsigned short h) {
    return __uint_as_float(((unsigned)h) << 16);
}
#define PK2(a, b) (((unsigned)(a)) | (((unsigned)(b)) << 16))

__device__ __forceinline__ f32x4 fmax4(f32x4 a, f32x4 b) {
    f32x4 r;
    r[0] = fmaxf(a[0], b[0]); r[1] = fmaxf(a[1], b[1]);
    r[2] = fmaxf(a[2], b[2]); r[3] = fmaxf(a[3], b[3]);
    return r;
}

// Raw v_exp_f32 = 2^x (Q is pre-scaled by log2e, so softmax is exp2-domain).
__device__ __forceinline__ float exp2_raw(float x) {
    float r;
    asm("v_exp_f32 %0, %1" : "=v"(r) : "v"(x));
    return r;
}

// ---------------------------------------------------------------------------
// Kernel 0: weight prep -> frag-ordered bf16 weights in ws.
//   whf: 20 groups x 8 kc x 64 lanes x 8 bf16  (g 0,1=q; 2,3=k; 4..19=v)
//   wlf: 4 groups (q,k lo part), same shape.
// q rows (g<2) pre-scaled by log2(e) so attn softmax can use raw v_exp.
// ---------------------------------------------------------------------------
__global__ __launch_bounds__(256) void wprep_kernel(
    const float* __restrict__ wq, const float* __restrict__ wk,
    const float* __restrict__ wv,
    unsigned short* __restrict__ whf, unsigned short* __restrict__ wlf)
{
    const int fid  = blockIdx.x * 256 + threadIdx.x;   // 0..10239
    if (fid >= 20 * 8 * 64) return;
    const int g    = fid >> 9;
    const int kc   = (fid >> 6) & 7;
    const int lane = fid & 63;
    const int r16  = lane & 15, q = lane >> 4;

    const float* src; int row;
    if (g < 2)      { src = wq; row = g * 16 + r16; }
    else if (g < 4) { src = wk; row = (g - 2) * 16 + r16; }
    else            { src = wv; row = (g - 4) * 16 + r16; }

    const float scl = (g < 2) ? LOG2E : 1.0f;
    const float* wp = src + row * 256 + kc * 32 + q * 8;
    float v[8];
#pragma unroll
    for (int j = 0; j < 8; ++j) v[j] = wp[j] * scl;

    unsigned short h[8];
#pragma unroll
    for (int j = 0; j < 8; ++j) h[j] = f2bf(v[j]);
    uint4 U;
    U.x = PK2(h[0], h[1]); U.y = PK2(h[2], h[3]);
    U.z = PK2(h[4], h[5]); U.w = PK2(h[6], h[7]);
    *(uint4*)&whf[(size_t)fid * 8] = U;

    if (g < 4) {
        unsigned short l[8];
#pragma unroll
        for (int j = 0; j < 8; ++j) l[j] = f2bf(v[j] - bf2f(h[j]));
        uint4 V;
        V.x = PK2(l[0], l[1]); V.y = PK2(l[2], l[3]);
        V.z = PK2(l[4], l[5]); V.w = PK2(l[6], l[7]);
        *(uint4*)&wlf[(size_t)fid * 8] = V;
    }
}

// ---------------------------------------------------------------------------
// Kernel 1: MFMA qkv projection (R10 structure, best measured — unchanged).
// 32-pixel tiles, grid (N/32, B) = 1024 blocks. Single-phase: stage ->
// barrier -> MFMA loop. Wave w owns qk-group g=w + v-groups 4+w*4...
// ---------------------------------------------------------------------------
__global__ __launch_bounds__(256, 4) void proj_kernel(
    const float* __restrict__ x,
    const float* __restrict__ bq, const float* __restrict__ bk,
    const float* __restrict__ bv,
    const unsigned short* __restrict__ whf, const unsigned short* __restrict__ wlf,
    unsigned short* __restrict__ qh, unsigned short* __restrict__ ql,
    unsigned short* __restrict__ kh, unsigned short* __restrict__ kl,
    unsigned short* __restrict__ vbf)
{
    __shared__ unsigned xpk[32 * 260 + 4];   // [pixel][c] packed (hi<<16|lo)

    const int tid  = threadIdx.x;
    const int w    = tid >> 6;        // wave 0..3
    const int lane = tid & 63;
    const int quad = lane >> 4;
    const int l16  = lane & 15;
    const int n0   = blockIdx.x * 32;
    const int b    = blockIdx.y;

    // ---- stage x tile: 32 pixels x 256 channels, bf16 hi/lo packed ----
    {
        const int p  = tid & 31;
        const int cb = tid >> 5;      // 0..7
        const float* xbase = x + (size_t)b * C_ * N_ + n0 + p;
#pragma unroll 16
        for (int s = 0; s < 32; ++s) {
            const int c = s * 8 + cb;
            const float v = xbase[(size_t)c * N_];
            const unsigned short hb = f2bf(v);
            const unsigned short lb = f2bf(v - bf2f(hb));
            xpk[p * 260 + c] = (((unsigned)hb) << 16) | lb;
        }
    }
    __syncthreads();

    const frag* wh = (const frag*)whf;
    const frag* wl = (const frag*)wlf;

    f32x4 aqk[2];        // [pixel-subtile] for qk group g=w
    f32x4 av[4][2];      // [v-group][pixel-subtile]
#pragma unroll
    for (int ps = 0; ps < 2; ++ps) {
        aqk[ps] = (f32x4){0.f, 0.f, 0.f, 0.f};
#pragma unroll
        for (int vg = 0; vg < 4; ++vg) av[vg][ps] = (f32x4){0.f, 0.f, 0.f, 0.f};
    }

    for (int kc = 0; kc < 8; ++kc) {
        // weight frags for this wave's groups (6 x 16B global, L2-hot)
        const frag ah = wh[(w * 8 + kc) * 64 + lane];
        const frag al = wl[(w * 8 + kc) * 64 + lane];
        frag avw[4];
#pragma unroll
        for (int vg = 0; vg < 4; ++vg)
            avw[vg] = wh[((4 + w * 4 + vg) * 8 + kc) * 64 + lane];

#pragma unroll
        for (int ps = 0; ps < 2; ++ps) {
            const unsigned* row = &xpk[(ps * 16 + l16) * 260 + kc * 32 + quad * 8];
            const uint4 A  = *(const uint4*)row;
            const uint4 Bv = *(const uint4*)(row + 4);
            frag bh, bl;
            unsigned* bhp = (unsigned*)&bh;
            unsigned* blp = (unsigned*)&bl;
            bhp[0] = __builtin_amdgcn_perm(A.y,  A.x,  0x07060302u);
            bhp[1] = __builtin_amdgcn_perm(A.w,  A.z,  0x07060302u);
            bhp[2] = __builtin_amdgcn_perm(Bv.y, Bv.x, 0x07060302u);
            bhp[3] = __builtin_amdgcn_perm(Bv.w, Bv.z, 0x07060302u);
            blp[0] = __builtin_amdgcn_perm(A.y,  A.x,  0x05040100u);
            blp[1] = __builtin_amdgcn_perm(A.w,  A.z,  0x05040100u);
            blp[2] = __builtin_amdgcn_perm(Bv.y, Bv.x, 0x05040100u);
            blp[3] = __builtin_amdgcn_perm(Bv.w, Bv.z, 0x05040100u);

            aqk[ps] = __builtin_amdgcn_mfma_f32_16x16x32_bf16(ah, bh, aqk[ps], 0, 0, 0);
            aqk[ps] = __builtin_amdgcn_mfma_f32_16x16x32_bf16(al, bh, aqk[ps], 0, 0, 0);
            aqk[ps] = __builtin_amdgcn_mfma_f32_16x16x32_bf16(ah, bl, aqk[ps], 0, 0, 0);
#pragma unroll
            for (int vg = 0; vg < 4; ++vg)
                av[vg][ps] = __builtin_amdgcn_mfma_f32_16x16x32_bf16(
                    avw[vg], bh, av[vg][ps], 0, 0, 0);
        }
    }

    // ---- epilogue: bias add, store ----
    {
        const bool isq = (w < 2);
        const float* bias = isq ? bq : bk;
        const float bscl = isq ? LOG2E : 1.0f;
        const int dbase = (isq ? w : w - 2) * 16 + quad * 4;
        unsigned short* dsth = isq ? qh : kh;
        unsigned short* dstl = isq ? ql : kl;
        float bvals[4];
#pragma unroll
        for (int r = 0; r < 4; ++r) bvals[r] = bias[dbase + r] * bscl;
#pragma unroll
        for (int ps = 0; ps < 2; ++ps) {
            const int n = n0 + ps * 16 + l16;
            unsigned short hs[4], ls[4];
#pragma unroll
            for (int r = 0; r < 4; ++r) {
                const float f = aqk[ps][r] + bvals[r];
                hs[r] = f2bf(f);
                ls[r] = f2bf(f - bf2f(hs[r]));
            }
            const size_t off = ((size_t)(b * N_ + n)) * 32 + dbase;
            *(uint2*)&dsth[off] = make_uint2(PK2(hs[0], hs[1]), PK2(hs[2], hs[3]));
            *(uint2*)&dstl[off] = make_uint2(PK2(ls[0], ls[1]), PK2(ls[2], ls[3]));
        }
    }
#pragma unroll
    for (int vg = 0; vg < 4; ++vg)
#pragma unroll
        for (int ps = 0; ps < 2; ++ps) {
            const int n = n0 + ps * 16 + l16;
#pragma unroll
            for (int r = 0; r < 4; ++r) {
                const int c = (w * 4 + vg) * 16 + quad * 4 + r;
                vbf[((size_t)b * C_ + c) * N_ + n] = f2bf(av[vg][ps][r] + bv[c]);
            }
        }
}

// ---------------------------------------------------------------------------
// Kernel 2: MFMA flash attention, WAVE-SPECIALIZED producer/consumer.
// R13: the lockstep 8-wave structure serialized three ~35%-busy pipes
// (every intra-phase edit was neutral; every tiling edit regressed). Now:
//   S-waves 0..3: rows w2*32..+32 each -- S^T (K frags shared across the 2
//     row-subtiles), online softmax, P-pack.  PV-waves 4..7: channels
//     w2*64..+64 each, ALL 128 rows -- rescale + PV, V loaded from L2
//     (XCD-pinned).
// Interval t: S produces tile t while PV consumes tile t-1 (p_s/alpha/kbuf
// parity identical to the proven lag-1 scheme). Each SIMD hosts 1 S-wave +
// 1 PV-wave -> softmax VALU overlaps PV MFMA across waves. One barrier per
// interval; NJC+1 intervals. Grid 256 XCD-pinned (b = bid&7). exp2 softmax.
// ---------------------------------------------------------------------------
__global__ __launch_bounds__(512, 2) void attn_kernel(
    const unsigned short* __restrict__ qh, const unsigned short* __restrict__ ql,
    const unsigned short* __restrict__ khg, const unsigned short* __restrict__ klg,
    const unsigned short* __restrict__ vbf,
    const float* __restrict__ x, const float* __restrict__ alpha_p,
    float* __restrict__ out)
{
    __shared__ __align__(16) short kbuf[2][2][128 * 32];   // 32 KB, [qc][row] chunks
    __shared__ __align__(16) short p_s[2][128 * PLD];      // ~69.6 KB
    __shared__ __align__(16) float alpha_s[2][128];
    __shared__ __align__(16) float l_s[128];

    const int tid  = threadIdx.x;
    const int w    = tid >> 6;        // wave 0..7
    const int lane = tid & 63;
    const int quad = lane >> 4;
    const int l16  = lane & 15;
    const int bid  = blockIdx.x;      // 0..255
    const int b    = bid & 7;         // batch pinned to XCD (id%8 round-robin)
    const int i0   = (bid >> 3) * 128;
    const bool isS = (w < 4);
    const int  w2  = w & 3;           // S: row-block index; PV: ch-block index

    const unsigned short* khb = khg + (size_t)b * N_ * 32;
    const unsigned short* klb = klg + (size_t)b * N_ * 32;
    const unsigned short* vb  = vbf + (size_t)b * C_ * N_;

    // ---- S-wave state: Q frags for rows w2*32 + s2*16 + l16 ----
    frag qhf[2], qlf[2];
    if (isS) {
#pragma unroll
        for (int s2 = 0; s2 < 2; ++s2) {
            const size_t qoff = ((size_t)(b * N_ + i0 + w2 * 32 + s2 * 16 + l16)) * 32
                                + quad * 8;
            qhf[s2] = *(const frag*)(qh + qoff);
            qlf[s2] = *(const frag*)(ql + qoff);
        }
    }
    float m_run[2] = {-INFINITY, -INFINITY};
    float l_run[2] = {0.f, 0.f};

    // ---- PV-wave state: O accumulators, rows it*16.., ch w2*64 + ct*16 + l16
    f32x4 o[8][4];
#pragma unroll
    for (int it = 0; it < 8; ++it)
#pragma unroll
        for (int ct = 0; ct < 4; ++ct)
            o[it][ct] = (f32x4){0.f, 0.f, 0.f, 0.f};

    // ---- K staging map (all 512 threads; conflict-free chunk layout) ----
    const int r_st  = w * 16 + l16;
    const int qc_st = quad;
    const int gsto  = r_st * 32 + qc_st * 8;
    const int lsto  = qc_st * 1024 + r_st * 8;

    // ---- prologue: stage K(0) into kbuf[0] ----
    {
        const uint4 h0 = *(const uint4*)(khb + gsto);
        const uint4 l0 = *(const uint4*)(klb + gsto);
        *(uint4*)&kbuf[0][0][lsto] = h0;
        *(uint4*)&kbuf[0][1][lsto] = l0;
    }
    __syncthreads();

    for (int t = 0; t <= NJC; ++t) {
        const int bf = t & 1;
        const bool do_stage = (t + 1 < NJC);
        uint4 knh, knl;
        if (do_stage) {
            knh = *(const uint4*)(khb + (size_t)(t + 1) * 4096 + gsto);
            knl = *(const uint4*)(klb + (size_t)(t + 1) * 4096 + gsto);
        }

        if (isS) {
            if (t < NJC) {
                // ---- S^T(t): K frags shared across the two row-subtiles ----
                f32x4 st0[8], st1[8];
#pragma unroll
                for (int js = 0; js < 8; ++js) {
                    const frag ka  = *(const frag*)&kbuf[bf][0][quad * 1024 + (js * 16 + l16) * 8];
                    const frag kb2 = *(const frag*)&kbuf[bf][1][quad * 1024 + (js * 16 + l16) * 8];
                    f32x4 s0 = (f32x4){0.f, 0.f, 0.f, 0.f};
                    s0 = __builtin_amdgcn_mfma_f32_16x16x32_bf16(ka,  qhf[0], s0, 0, 0, 0);
                    s0 = __builtin_amdgcn_mfma_f32_16x16x32_bf16(ka,  qlf[0], s0, 0, 0, 0);
                    s0 = __builtin_amdgcn_mfma_f32_16x16x32_bf16(kb2, qhf[0], s0, 0, 0, 0);
                    st0[js] = s0;
                    f32x4 s1 = (f32x4){0.f, 0.f, 0.f, 0.f};
                    s1 = __builtin_amdgcn_mfma_f32_16x16x32_bf16(ka,  qhf[1], s1, 0, 0, 0);
                    s1 = __builtin_amdgcn_mfma_f32_16x16x32_bf16(ka,  qlf[1], s1, 0, 0, 0);
                    s1 = __builtin_amdgcn_mfma_f32_16x16x32_bf16(kb2, qhf[1], s1, 0, 0, 0);
                    st1[js] = s1;
                }

                // ---- softmax + pack, per row-subtile s2 ----
#pragma unroll
                for (int s2 = 0; s2 < 2; ++s2) {
                    f32x4* st = s2 ? st1 : st0;
                    f32x4 t0v = fmax4(fmax4(st[0], st[1]), fmax4(st[2], st[3]));
                    f32x4 t1v = fmax4(fmax4(st[4], st[5]), fmax4(st[6], st[7]));
                    t0v = fmax4(t0v, t1v);
                    float mx = fmaxf(fmaxf(t0v[0], t0v[1]), fmaxf(t0v[2], t0v[3]));
                    mx = fmaxf(mx, __shfl_xor(mx, 16));
                    mx = fmaxf(mx, __shfl_xor(mx, 32));
                    const float mnew = fmaxf(m_run[s2], mx);
                    const float sc   = exp2_raw(m_run[s2] - mnew);

                    f32x4 ps4 = (f32x4){0.f, 0.f, 0.f, 0.f};
#pragma unroll
                    for (int js = 0; js < 8; ++js) {
#pragma unroll
                        for (int r = 0; r < 4; ++r) st[js][r] = exp2_raw(st[js][r] - mnew);
                        ps4[0] += st[js][0]; ps4[1] += st[js][1];
                        ps4[2] += st[js][2]; ps4[3] += st[js][3];
                    }
                    float ps = (ps4[0] + ps4[1]) + (ps4[2] + ps4[3]);
                    ps += __shfl_xor(ps, 16);
                    ps += __shfl_xor(ps, 32);
                    l_run[s2] = l_run[s2] * sc + ps;
                    m_run[s2] = mnew;
                    const int row = w2 * 32 + s2 * 16 + l16;
                    if (quad == 0) alpha_s[bf][row] = sc;

#pragma unroll
                    for (int js = 0; js < 8; ++js) {
                        const unsigned a0 = __float_as_uint(st[js][0]) + 0x8000u;
                        const unsigned a1 = __float_as_uint(st[js][1]) + 0x8000u;
                        const unsigned a2 = __float_as_uint(st[js][2]) + 0x8000u;
                        const unsigned a3 = __float_as_uint(st[js][3]) + 0x8000u;
                        const unsigned p01 = __builtin_amdgcn_perm(a1, a0, 0x07060302u);
                        const unsigned p23 = __builtin_amdgcn_perm(a3, a2, 0x07060302u);
                        *(uint2*)&p_s[bf][row * PLD + js * 16 + quad * 4] =
                            make_uint2(p01, p23);
                    }
                }
            } else {
                // final interval: publish l for the epilogue
                if (quad == 0) {
                    l_s[w2 * 32 + l16]      = l_run[0];
                    l_s[w2 * 32 + 16 + l16] = l_run[1];
                }
            }
        } else {
            if (t > 0) {
                const int pb = bf ^ 1;   // parity of tile t-1

                // ---- V(t-1) loads (L2-hot, XCD-pinned) ----
                frag vf[4][4];
#pragma unroll
                for (int ks = 0; ks < 4; ++ks)
#pragma unroll
                    for (int ct = 0; ct < 4; ++ct)
                        vf[ks][ct] = *(const frag*)(vb
                            + (size_t)(w2 * 64 + ct * 16 + l16) * N_
                            + (size_t)(t - 1) * 128 + ks * 32 + quad * 8);

                // ---- rescale O by alpha(t-1), f32x4 reads ----
#pragma unroll
                for (int it = 0; it < 8; ++it) {
                    const f32x4 alf = *(const f32x4*)&alpha_s[pb][it * 16 + quad * 4];
#pragma unroll
                    for (int r = 0; r < 4; ++r) {
#pragma unroll
                        for (int ct = 0; ct < 4; ++ct) o[it][ct][r] *= alf[r];
                    }
                }

                // ---- PV(t-1): A = P (LDS), B = V regs ----
#pragma unroll
                for (int ks = 0; ks < 4; ++ks) {
#pragma unroll
                    for (int it = 0; it < 8; ++it) {
                        const frag pf = *(const frag*)&p_s[pb][(it * 16 + l16) * PLD
                                                               + ks * 32 + quad * 8];
#pragma unroll
                        for (int ct = 0; ct < 4; ++ct)
                            o[it][ct] = __builtin_amdgcn_mfma_f32_16x16x32_bf16(
                                pf, vf[ks][ct], o[it][ct], 0, 0, 0);
                    }
                }
            }
        }

        if (do_stage) {
            *(uint4*)&kbuf[bf ^ 1][0][lsto] = knh;
            *(uint4*)&kbuf[bf ^ 1][1][lsto] = knl;
        }
        __syncthreads();
    }

    // ---- epilogue (PV-waves): out = alpha * O / l + x ----
    if (!isS) {
        const float av = alpha_p[0];
#pragma unroll
        for (int it = 0; it < 8; ++it) {
            const f32x4 lv = *(const f32x4*)&l_s[it * 16 + quad * 4];
            float invl[4];
#pragma unroll
            for (int r = 0; r < 4; ++r) invl[r] = 1.f / lv[r];
#pragma unroll
            for (int ct = 0; ct < 4; ++ct) {
                const int c = w2 * 64 + ct * 16 + l16;
                const size_t base = (size_t)b * C_ * N_ + (size_t)c * N_
                                    + i0 + it * 16 + quad * 4;
                const float4 xv = *(const float4*)(x + base);
                float4 ov;
                ov.x = av * (o[it][ct][0] * invl[0]) + xv.x;
                ov.y = av * (o[it][ct][1] * invl[1]) + xv.y;
                ov.z = av * (o[it][ct][2] * invl[2]) + xv.z;
                ov.w = av * (o[it][ct][3] * invl[3]) + xv.w;
                *(float4*)(out + base) = ov;
            }
        }
    }
}

// ---------------------------------------------------------------------------
extern "C" void kernel_launch(void* const* d_in, const int* in_sizes, int n_in,
                              void* d_out, int out_size, void* d_ws, size_t ws_size,
                              hipStream_t stream)
{
    const float* x  = (const float*)d_in[0];
    const float* wq = (const float*)d_in[1];
    const float* bq = (const float*)d_in[2];
    const float* wk = (const float*)d_in[3];
    const float* bk = (const float*)d_in[4];
    const float* wv = (const float*)d_in[5];
    const float* bv = (const float*)d_in[6];
    const float* al = (const float*)d_in[7];
    float* out = (float*)d_out;

    // workspace: qh,ql,kh,kl 2MB each; vbf 16MB; whf 160KB; wlf 32KB
    char* ws = (char*)d_ws;
    unsigned short* qh  = (unsigned short*)(ws + 0);
    unsigned short* ql  = (unsigned short*)(ws + (size_t)2  * 1024 * 1024);
    unsigned short* kh  = (unsigned short*)(ws + (size_t)4  * 1024 * 1024);
    unsigned short* kl  = (unsigned short*)(ws + (size_t)6  * 1024 * 1024);
    unsigned short* vbf = (unsigned short*)(ws + (size_t)8  * 1024 * 1024);
    unsigned short* whf = (unsigned short*)(ws + (size_t)24 * 1024 * 1024);
    unsigned short* wlf = (unsigned short*)(ws + (size_t)24 * 1024 * 1024 + 256 * 1024);

    wprep_kernel<<<40, 256, 0, stream>>>(wq, wk, wv, whf, wlf);
    proj_kernel<<<dim3(N_ / 32, B_), 256, 0, stream>>>(
        x, bq, bk, bv, whf, wlf, qh, ql, kh, kl, vbf);
    attn_kernel<<<dim3(256), 512, 0, stream>>>(
        qh, ql, kh, kl, vbf, x, al, out);
}

// Round 14
// 206.806 us; speedup vs baseline: 1.3971x; 1.3971x over previous
//
#include <hip/hip_runtime.h>
#include <math.h>

// Problem constants (fixed by the reference)
#define B_  8
#define C_  256
#define N_  4096        // H*W
#define NJC (N_ / 128)  // 32 j-iterations of 128
#define PLD 136         // p_s row stride in shorts (128 + 8 pad)
#define LOG2E 1.4426950408889634f

using frag  = __attribute__((ext_vector_type(8))) short;   // 8 bf16 = 16 B
using f32x4 = __attribute__((ext_vector_type(4))) float;

__device__ __forceinline__ unsigned short f2bf(float f) {   // RNE fp32 -> bf16
    unsigned u = __float_as_uint(f);
    u += 0x7fffu + ((u >> 16) & 1u);
    return (unsigned short)(u >> 16);
}
__device__ __forceinline__ float bf2f(unsigned short h) {
    return __uint_as_float(((unsigned)h) << 16);
}
#define PK2(a, b) (((unsigned)(a)) | (((unsigned)(b)) << 16))

__device__ __forceinline__ f32x4 fmax4(f32x4 a, f32x4 b) {
    f32x4 r;
    r[0] = fmaxf(a[0], b[0]); r[1] = fmaxf(a[1], b[1]);
    r[2] = fmaxf(a[2], b[2]); r[3] = fmaxf(a[3], b[3]);
    return r;
}

// Raw v_exp_f32 = 2^x (Q is pre-scaled by log2e, so softmax is exp2-domain).
__device__ __forceinline__ float exp2_raw(float x) {
    float r;
    asm("v_exp_f32 %0, %1" : "=v"(r) : "v"(x));
    return r;
}

// ---------------------------------------------------------------------------
// Kernel 0: weight prep -> frag-ordered bf16 weights in ws.
//   whf: 20 groups x 8 kc x 64 lanes x 8 bf16  (g 0,1=q; 2,3=k; 4..19=v)
//   wlf: 4 groups (q,k lo part), same shape.
// q rows (g<2) pre-scaled by log2(e) so attn softmax can use raw v_exp.
// ---------------------------------------------------------------------------
__global__ __launch_bounds__(256) void wprep_kernel(
    const float* __restrict__ wq, const float* __restrict__ wk,
    const float* __restrict__ wv,
    unsigned short* __restrict__ whf, unsigned short* __restrict__ wlf)
{
    const int fid  = blockIdx.x * 256 + threadIdx.x;   // 0..10239
    if (fid >= 20 * 8 * 64) return;
    const int g    = fid >> 9;
    const int kc   = (fid >> 6) & 7;
    const int lane = fid & 63;
    const int r16  = lane & 15, q = lane >> 4;

    const float* src; int row;
    if (g < 2)      { src = wq; row = g * 16 + r16; }
    else if (g < 4) { src = wk; row = (g - 2) * 16 + r16; }
    else            { src = wv; row = (g - 4) * 16 + r16; }

    const float scl = (g < 2) ? LOG2E : 1.0f;
    const float* wp = src + row * 256 + kc * 32 + q * 8;
    float v[8];
#pragma unroll
    for (int j = 0; j < 8; ++j) v[j] = wp[j] * scl;

    unsigned short h[8];
#pragma unroll
    for (int j = 0; j < 8; ++j) h[j] = f2bf(v[j]);
    uint4 U;
    U.x = PK2(h[0], h[1]); U.y = PK2(h[2], h[3]);
    U.z = PK2(h[4], h[5]); U.w = PK2(h[6], h[7]);
    *(uint4*)&whf[(size_t)fid * 8] = U;

    if (g < 4) {
        unsigned short l[8];
#pragma unroll
        for (int j = 0; j < 8; ++j) l[j] = f2bf(v[j] - bf2f(h[j]));
        uint4 V;
        V.x = PK2(l[0], l[1]); V.y = PK2(l[2], l[3]);
        V.z = PK2(l[4], l[5]); V.w = PK2(l[6], l[7]);
        *(uint4*)&wlf[(size_t)fid * 8] = V;
    }
}

// ---------------------------------------------------------------------------
// Kernel 1: MFMA qkv projection (R10 structure; R14: float4 x-staging).
// 32-pixel tiles, grid (N/32, B) = 1024 blocks. Single-phase: stage ->
// barrier -> MFMA loop. Wave w owns qk-group g=w (3 MFMA split-bf16) +
// v-groups 4+w*4.. (1 MFMA each) for 32 pixels (ps=0..1).
// R14 CHANGE: staging was 32 scalar dword loads/thread (32 independent
// ~HBM-latency events, scalar-load anti-pattern); now 8 x float4 loads
// (4 consecutive pixels each, 16B/lane, 128B-coalesced rows). LDS layout
// and all compute unchanged. q pre-scaled by log2e.
// ---------------------------------------------------------------------------
__global__ __launch_bounds__(256, 4) void proj_kernel(
    const float* __restrict__ x,
    const float* __restrict__ bq, const float* __restrict__ bk,
    const float* __restrict__ bv,
    const unsigned short* __restrict__ whf, const unsigned short* __restrict__ wlf,
    unsigned short* __restrict__ qh, unsigned short* __restrict__ ql,
    unsigned short* __restrict__ kh, unsigned short* __restrict__ kl,
    unsigned short* __restrict__ vbf)
{
    __shared__ unsigned xpk[32 * 260 + 4];   // [pixel][c] packed (hi<<16|lo)

    const int tid  = threadIdx.x;
    const int w    = tid >> 6;        // wave 0..3
    const int lane = tid & 63;
    const int quad = lane >> 4;
    const int l16  = lane & 15;
    const int n0   = blockIdx.x * 32;
    const int b    = blockIdx.y;

    // ---- stage x tile: 32 pixels x 256 channels, float4 loads ----
    {
        const int pg = (tid & 7) * 4;     // pixel-group base: 0,4,...,28
        const int c0 = tid >> 3;          // 0..31
        const float* xb = x + (size_t)b * C_ * N_ + n0 + pg;
#pragma unroll
        for (int s = 0; s < 8; ++s) {
            const int c = s * 32 + c0;
            const float4 v4 = *(const float4*)(xb + (size_t)c * N_);
            const float vv[4] = {v4.x, v4.y, v4.z, v4.w};
#pragma unroll
            for (int j = 0; j < 4; ++j) {
                const unsigned short hb = f2bf(vv[j]);
                const unsigned short lb = f2bf(vv[j] - bf2f(hb));
                xpk[(pg + j) * 260 + c] = (((unsigned)hb) << 16) | lb;
            }
        }
    }
    __syncthreads();

    const frag* wh = (const frag*)whf;
    const frag* wl = (const frag*)wlf;

    f32x4 aqk[2];        // [pixel-subtile] for qk group g=w
    f32x4 av[4][2];      // [v-group][pixel-subtile]
#pragma unroll
    for (int ps = 0; ps < 2; ++ps) {
        aqk[ps] = (f32x4){0.f, 0.f, 0.f, 0.f};
#pragma unroll
        for (int vg = 0; vg < 4; ++vg) av[vg][ps] = (f32x4){0.f, 0.f, 0.f, 0.f};
    }

    for (int kc = 0; kc < 8; ++kc) {
        // weight frags for this wave's groups (6 x 16B global, L2-hot)
        const frag ah = wh[(w * 8 + kc) * 64 + lane];
        const frag al = wl[(w * 8 + kc) * 64 + lane];
        frag avw[4];
#pragma unroll
        for (int vg = 0; vg < 4; ++vg)
            avw[vg] = wh[((4 + w * 4 + vg) * 8 + kc) * 64 + lane];

#pragma unroll
        for (int ps = 0; ps < 2; ++ps) {
            const unsigned* row = &xpk[(ps * 16 + l16) * 260 + kc * 32 + quad * 8];
            const uint4 A  = *(const uint4*)row;
            const uint4 Bv = *(const uint4*)(row + 4);
            frag bh, bl;
            unsigned* bhp = (unsigned*)&bh;
            unsigned* blp = (unsigned*)&bl;
            bhp[0] = __builtin_amdgcn_perm(A.y,  A.x,  0x07060302u);
            bhp[1] = __builtin_amdgcn_perm(A.w,  A.z,  0x07060302u);
            bhp[2] = __builtin_amdgcn_perm(Bv.y, Bv.x, 0x07060302u);
            bhp[3] = __builtin_amdgcn_perm(Bv.w, Bv.z, 0x07060302u);
            blp[0] = __builtin_amdgcn_perm(A.y,  A.x,  0x05040100u);
            blp[1] = __builtin_amdgcn_perm(A.w,  A.z,  0x05040100u);
            blp[2] = __builtin_amdgcn_perm(Bv.y, Bv.x, 0x05040100u);
            blp[3] = __builtin_amdgcn_perm(Bv.w, Bv.z, 0x05040100u);

            aqk[ps] = __builtin_amdgcn_mfma_f32_16x16x32_bf16(ah, bh, aqk[ps], 0, 0, 0);
            aqk[ps] = __builtin_amdgcn_mfma_f32_16x16x32_bf16(al, bh, aqk[ps], 0, 0, 0);
            aqk[ps] = __builtin_amdgcn_mfma_f32_16x16x32_bf16(ah, bl, aqk[ps], 0, 0, 0);
#pragma unroll
            for (int vg = 0; vg < 4; ++vg)
                av[vg][ps] = __builtin_amdgcn_mfma_f32_16x16x32_bf16(
                    avw[vg], bh, av[vg][ps], 0, 0, 0);
        }
    }

    // ---- epilogue: bias add, store ----
    {
        const bool isq = (w < 2);
        const float* bias = isq ? bq : bk;
        const float bscl = isq ? LOG2E : 1.0f;
        const int dbase = (isq ? w : w - 2) * 16 + quad * 4;
        unsigned short* dsth = isq ? qh : kh;
        unsigned short* dstl = isq ? ql : kl;
        float bvals[4];
#pragma unroll
        for (int r = 0; r < 4; ++r) bvals[r] = bias[dbase + r] * bscl;
#pragma unroll
        for (int ps = 0; ps < 2; ++ps) {
            const int n = n0 + ps * 16 + l16;
            unsigned short hs[4], ls[4];
#pragma unroll
            for (int r = 0; r < 4; ++r) {
                const float f = aqk[ps][r] + bvals[r];
                hs[r] = f2bf(f);
                ls[r] = f2bf(f - bf2f(hs[r]));
            }
            const size_t off = ((size_t)(b * N_ + n)) * 32 + dbase;
            *(uint2*)&dsth[off] = make_uint2(PK2(hs[0], hs[1]), PK2(hs[2], hs[3]));
            *(uint2*)&dstl[off] = make_uint2(PK2(ls[0], ls[1]), PK2(ls[2], ls[3]));
        }
    }
#pragma unroll
    for (int vg = 0; vg < 4; ++vg)
#pragma unroll
        for (int ps = 0; ps < 2; ++ps) {
            const int n = n0 + ps * 16 + l16;
#pragma unroll
            for (int r = 0; r < 4; ++r) {
                const int c = (w * 4 + vg) * 16 + quad * 4 + r;
                vbf[((size_t)b * C_ + c) * N_ + n] = f2bf(av[vg][ps][r] + bv[c]);
            }
        }
}

// ---------------------------------------------------------------------------
// Kernel 2: MFMA flash attention, PV-lag-1 + XCD pinning (R11 verbatim —
// session-best, 118.5us, stable across 5 runs). 128-row i-tile, 8 waves.
// PV delayed one j-iteration; kbuf conflict-free [quad-col][row] chunks;
// p_s dbuf; exp2-domain softmax; grid 256 flattened, b = bid&7 pins each
// batch to one XCD (FETCH 100->29MB, measured).
// NOTE (session record): 2-D PV tiling (R5/R12), 4-wave blocks (R2), and
// producer/consumer wave split (R13) ALL regressed 35-78us — the lockstep
// barrier cadence makes this body a strong local optimum; do not restructure
// without a fundamentally different sync scheme.
// ---------------------------------------------------------------------------
__global__ __launch_bounds__(512, 2) void attn_kernel(
    const unsigned short* __restrict__ qh, const unsigned short* __restrict__ ql,
    const unsigned short* __restrict__ khg, const unsigned short* __restrict__ klg,
    const unsigned short* __restrict__ vbf,
    const float* __restrict__ x, const float* __restrict__ alpha_p,
    float* __restrict__ out)
{
    __shared__ __align__(16) short kbuf[2][2][128 * 32];   // 32 KB, [qc][row] chunks
    __shared__ __align__(16) short p_s[2][128 * PLD];      // ~69.6 KB
    __shared__ float alpha_s[2][128];
    __shared__ float l_s[128];

    const int tid  = threadIdx.x;
    const int w    = tid >> 6;        // wave 0..7
    const int lane = tid & 63;
    const int quad = lane >> 4;
    const int l16  = lane & 15;
    const int bid  = blockIdx.x;      // 0..255
    const int b    = bid & 7;         // batch pinned to XCD (id%8 round-robin)
    const int i0   = (bid >> 3) * 128;

    // Q B-frags (constant): lane holds q[i = i0+16w+l16][d = 8*quad..+8]
    const size_t qoff = ((size_t)(b * N_ + i0 + w * 16 + l16)) * 32 + quad * 8;
    const frag qhf = *(const frag*)(qh + qoff);
    const frag qlf = *(const frag*)(ql + qoff);

    const unsigned short* khb = khg + (size_t)b * N_ * 32;
    const unsigned short* klb = klg + (size_t)b * N_ * 32;
    const unsigned short* vb  = vbf + (size_t)b * C_ * N_;

    f32x4 o[8][2];   // [i-subtile][c-subtile], c = w*32 + ct*16 + l16
#pragma unroll
    for (int it = 0; it < 8; ++it) {
        o[it][0] = (f32x4){0.f, 0.f, 0.f, 0.f};
        o[it][1] = (f32x4){0.f, 0.f, 0.f, 0.f};
    }

    float m_run = -INFINITY, l_run = 0.f;

    // ---- K staging map (conflict-free LDS layout): lane stages chunk
    // (r = w*16+l16, qc = quad); global 16B at r*32+qc*8 shorts, LDS 16B at
    // qc*1024 + r*8 shorts.
    const int r_st  = w * 16 + l16;
    const int qc_st = quad;
    const int gsto  = r_st * 32 + qc_st * 8;
    const int lsto  = qc_st * 1024 + r_st * 8;

    // V fragments of iter jc, consumed at iter jc+1 (or epilogue).
    frag vf[4][2];

    // ---- prologue: stage K(0) into kbuf[0] ----
    {
        const uint4 h0 = *(const uint4*)(khb + gsto);
        const uint4 l0 = *(const uint4*)(klb + gsto);
        *(uint4*)&kbuf[0][0][lsto] = h0;
        *(uint4*)&kbuf[0][1][lsto] = l0;
    }
    __syncthreads();

    for (int jc = 0; jc < NJC; ++jc) {
        const int bf = jc & 1;

        // ---- S^T(jc) from kbuf[bf] (3-MFMA split-bf16), D[m=j][n=i] ----
        f32x4 st[8];
#pragma unroll
        for (int js = 0; js < 8; ++js) {
            const frag ka  = *(const frag*)&kbuf[bf][0][quad * 1024 + (js * 16 + l16) * 8];
            const frag kb2 = *(const frag*)&kbuf[bf][1][quad * 1024 + (js * 16 + l16) * 8];
            f32x4 s = (f32x4){0.f, 0.f, 0.f, 0.f};
            s = __builtin_amdgcn_mfma_f32_16x16x32_bf16(ka, qhf, s, 0, 0, 0);
            s = __builtin_amdgcn_mfma_f32_16x16x32_bf16(ka, qlf, s, 0, 0, 0);
            s = __builtin_amdgcn_mfma_f32_16x16x32_bf16(kb2, qhf, s, 0, 0, 0);
            st[js] = s;
        }

        // ---- issue K(jc+1) global->regs ----
        const int jn = (jc + 1 < NJC) ? jc + 1 : jc;
        const uint4 knh = *(const uint4*)(khb + (size_t)jn * 4096 + gsto);
        const uint4 knl = *(const uint4*)(klb + (size_t)jn * 4096 + gsto);

        // ---- lag-1 PV: rescale by alpha(jc-1), then PV(jc-1).
        // p_s[bf^1] and alpha_s[bf^1] were written in iter jc-1 (pre-barrier);
        // vf still holds V(jc-1). ----
        if (jc > 0) {
#pragma unroll
            for (int it = 0; it < 8; ++it)
#pragma unroll
                for (int r = 0; r < 4; ++r) {
                    const float al = alpha_s[bf ^ 1][it * 16 + quad * 4 + r];
                    o[it][0][r] *= al;
                    o[it][1][r] *= al;
                }
#pragma unroll
            for (int ks = 0; ks < 4; ++ks) {
#pragma unroll
                for (int it = 0; it < 8; ++it) {
                    const frag pf = *(const frag*)&p_s[bf ^ 1][(it * 16 + l16) * PLD
                                                              + ks * 32 + quad * 8];
                    o[it][0] = __builtin_amdgcn_mfma_f32_16x16x32_bf16(pf, vf[ks][0], o[it][0], 0, 0, 0);
                    o[it][1] = __builtin_amdgcn_mfma_f32_16x16x32_bf16(pf, vf[ks][1], o[it][1], 0, 0, 0);
                }
            }
        }

        // ---- load V(jc) -> vf (consumed at jc+1 / epilogue; a full
        // iteration of latency slack).  c = w*32 + ct*16 + l16 ----
#pragma unroll
        for (int ks = 0; ks < 4; ++ks)
#pragma unroll
            for (int ct = 0; ct < 2; ++ct)
                vf[ks][ct] = *(const frag*)(vb
                    + (size_t)(w * 32 + ct * 16 + l16) * N_
                    + jc * 128 + ks * 32 + quad * 8);

        // ---- online softmax (exp2 domain), rows i = w*16 + l16 ----
        f32x4 t0 = fmax4(fmax4(st[0], st[1]), fmax4(st[2], st[3]));
        f32x4 t1 = fmax4(fmax4(st[4], st[5]), fmax4(st[6], st[7]));
        t0 = fmax4(t0, t1);
        float mx = fmaxf(fmaxf(t0[0], t0[1]), fmaxf(t0[2], t0[3]));
        mx = fmaxf(mx, __shfl_xor(mx, 16));
        mx = fmaxf(mx, __shfl_xor(mx, 32));
        const float mnew = fmaxf(m_run, mx);
        const float sc   = exp2_raw(m_run - mnew);

        f32x4 ps4 = (f32x4){0.f, 0.f, 0.f, 0.f};
#pragma unroll
        for (int js = 0; js < 8; ++js) {
#pragma unroll
            for (int r = 0; r < 4; ++r) st[js][r] = exp2_raw(st[js][r] - mnew);
            ps4[0] += st[js][0]; ps4[1] += st[js][1];
            ps4[2] += st[js][2]; ps4[3] += st[js][3];
        }
        float ps = (ps4[0] + ps4[1]) + (ps4[2] + ps4[3]);
        ps += __shfl_xor(ps, 16);
        ps += __shfl_xor(ps, 32);
        l_run = l_run * sc + ps;
        m_run = mnew;
        if (quad == 0) alpha_s[bf][w * 16 + l16] = sc;

        // ---- P -> bf16 (round-half-up + v_perm pack) -> p_s[bf] ----
#pragma unroll
        for (int js = 0; js < 8; ++js) {
            const unsigned a0 = __float_as_uint(st[js][0]) + 0x8000u;
            const unsigned a1 = __float_as_uint(st[js][1]) + 0x8000u;
            const unsigned a2 = __float_as_uint(st[js][2]) + 0x8000u;
            const unsigned a3 = __float_as_uint(st[js][3]) + 0x8000u;
            const unsigned p01 = __builtin_amdgcn_perm(a1, a0, 0x07060302u);
            const unsigned p23 = __builtin_amdgcn_perm(a3, a2, 0x07060302u);
            *(uint2*)&p_s[bf][(w * 16 + l16) * PLD + js * 16 + quad * 4] =
                make_uint2(p01, p23);
        }

        // ---- stage K(jc+1) into kbuf[bf^1] ----
        *(uint4*)&kbuf[bf ^ 1][0][lsto] = knh;
        *(uint4*)&kbuf[bf ^ 1][1][lsto] = knl;

        __syncthreads();   // single barrier per iter
    }

    // ---- epilogue part 1: final rescale + PV(NJC-1) ----
    {
        const int bl = (NJC - 1) & 1;
#pragma unroll
        for (int it = 0; it < 8; ++it)
#pragma unroll
            for (int r = 0; r < 4; ++r) {
                const float al = alpha_s[bl][it * 16 + quad * 4 + r];
                o[it][0][r] *= al;
                o[it][1][r] *= al;
            }
#pragma unroll
        for (int ks = 0; ks < 4; ++ks) {
#pragma unroll
            for (int it = 0; it < 8; ++it) {
                const frag pf = *(const frag*)&p_s[bl][(it * 16 + l16) * PLD
                                                       + ks * 32 + quad * 8];
                o[it][0] = __builtin_amdgcn_mfma_f32_16x16x32_bf16(pf, vf[ks][0], o[it][0], 0, 0, 0);
                o[it][1] = __builtin_amdgcn_mfma_f32_16x16x32_bf16(pf, vf[ks][1], o[it][1], 0, 0, 0);
            }
        }
    }

    // ---- epilogue part 2: out = alpha * O / l + x ----
    if (quad == 0) l_s[w * 16 + l16] = l_run;
    __syncthreads();
    const float av = alpha_p[0];

#pragma unroll
    for (int it = 0; it < 8; ++it) {
        float invl[4];
#pragma unroll
        for (int r = 0; r < 4; ++r) invl[r] = 1.f / l_s[it * 16 + quad * 4 + r];
#pragma unroll
        for (int ct = 0; ct < 2; ++ct) {
            const int c = w * 32 + ct * 16 + l16;
            const size_t base = (size_t)b * C_ * N_ + (size_t)c * N_
                                + i0 + it * 16 + quad * 4;
            const float4 xv = *(const float4*)(x + base);
            float4 ov;
            ov.x = av * (o[it][ct][0] * invl[0]) + xv.x;
            ov.y = av * (o[it][ct][1] * invl[1]) + xv.y;
            ov.z = av * (o[it][ct][2] * invl[2]) + xv.z;
            ov.w = av * (o[it][ct][3] * invl[3]) + xv.w;
            *(float4*)(out + base) = ov;
        }
    }
}

// ---------------------------------------------------------------------------
extern "C" void kernel_launch(void* const* d_in, const int* in_sizes, int n_in,
                              void* d_out, int out_size, void* d_ws, size_t ws_size,
                              hipStream_t stream)
{
    const float* x  = (const float*)d_in[0];
    const float* wq = (const float*)d_in[1];
    const float* bq = (const float*)d_in[2];
    const float* wk = (const float*)d_in[3];
    const float* bk = (const float*)d_in[4];
    const float* wv = (const float*)d_in[5];
    const float* bv = (const float*)d_in[6];
    const float* al = (const float*)d_in[7];
    float* out = (float*)d_out;

    // workspace: qh,ql,kh,kl 2MB each; vbf 16MB; whf 160KB; wlf 32KB
    char* ws = (char*)d_ws;
    unsigned short* qh  = (unsigned short*)(ws + 0);
    unsigned short* ql  = (unsigned short*)(ws + (size_t)2  * 1024 * 1024);
    unsigned short* kh  = (unsigned short*)(ws + (size_t)4  * 1024 * 1024);
    unsigned short* kl  = (unsigned short*)(ws + (size_t)6  * 1024 * 1024);
    unsigned short* vbf = (unsigned short*)(ws + (size_t)8  * 1024 * 1024);
    unsigned short* whf = (unsigned short*)(ws + (size_t)24 * 1024 * 1024);
    unsigned short* wlf = (unsigned short*)(ws + (size_t)24 * 1024 * 1024 + 256 * 1024);

    wprep_kernel<<<40, 256, 0, stream>>>(wq, wk, wv, whf, wlf);
    proj_kernel<<<dim3(N_ / 32, B_), 256, 0, stream>>>(
        x, bq, bk, bv, whf, wlf, qh, ql, kh, kl, vbf);
    attn_kernel<<<dim3(256), 512, 0, stream>>>(
        qh, ql, kh, kl, vbf, x, al, out);
}